// Round 1
// baseline (675.853 us; speedup 1.0000x reference)
//
#include <hip/hip_runtime.h>

#define NUM_BUCKETS 2000003
#define HASH_MULT   92821
#define SEQ         8192
#define NTOK        32768          // 4 * 8192
#define MDIM        1024
#define HDIM        64
#define TT          64             // tokens per block

// Pre-kernel: compute bucket ids once (64-bit mod is ~30 instrs; don't
// duplicate it across the 16 dim-chunk waves that touch each token).
__global__ __launch_bounds__(256) void hash_kernel(const int* __restrict__ ids,
                                                   int* __restrict__ hbuf) {
    int t = blockIdx.x * 256 + threadIdx.x;
    if (t >= NTOK) return;
    unsigned long long cur  = (unsigned long long)(unsigned int)ids[t];
    unsigned long long prev = ((t & (SEQ - 1)) == 0)
                                  ? 0ull
                                  : (unsigned long long)(unsigned int)ids[t - 1];
    hbuf[t] = (int)((prev * (unsigned long long)HASH_MULT + cur) %
                    (unsigned long long)NUM_BUCKETS);
}

// Main kernel: wave owns 64 consecutive model dims. Lane m holds proj_w row m
// (64 f32) in VGPRs; per token the embedding row is wave-uniform (scalarized
// 256 B load), 64 fp32 FMA per lane, one coalesced 256 B store per wave.
__global__ __launch_bounds__(256) void bigram_kernel(const int*   __restrict__ hbuf,
                                                     const float* __restrict__ table,
                                                     const float* __restrict__ W,
                                                     float*       __restrict__ out) {
    const int lane = threadIdx.x & 63;
    const int wid  = threadIdx.x >> 6;
    const int m    = blockIdx.y * 256 + wid * 64 + lane;   // model dim for this lane

    // proj_w row -> 16 float4 in VGPRs (once per wave lifetime, reused TT times)
    float4 w[16];
    const float4* Wv = (const float4*)(W + (size_t)m * HDIM);
#pragma unroll
    for (int i = 0; i < 16; ++i) w[i] = Wv[i];

    const int t0 = blockIdx.x * TT;
    for (int tt = 0; tt < TT; ++tt) {
        const int t = t0 + tt;
        // bucket id is the same for all lanes -> force uniformity so the
        // embedding-row loads scalarize (s_load) / broadcast-coalesce.
        const int h = __builtin_amdgcn_readfirstlane(hbuf[t]);
        const float4* e = (const float4*)(table + (size_t)h * HDIM);

        // 4 independent accumulator chains (dependent v_fma is ~4 cyc; a
        // single 64-deep chain would be latency-bound).
        float4 acc = {0.f, 0.f, 0.f, 0.f};
#pragma unroll
        for (int k = 0; k < 16; ++k) {
            float4 ev = e[k];
            acc.x = fmaf(w[k].x, ev.x, acc.x);
            acc.y = fmaf(w[k].y, ev.y, acc.y);
            acc.z = fmaf(w[k].z, ev.z, acc.z);
            acc.w = fmaf(w[k].w, ev.w, acc.w);
        }
        out[(size_t)t * MDIM + m] = (acc.x + acc.y) + (acc.z + acc.w);
    }
}

extern "C" void kernel_launch(void* const* d_in, const int* in_sizes, int n_in,
                              void* d_out, int out_size, void* d_ws, size_t ws_size,
                              hipStream_t stream) {
    const int*   ids   = (const int*)d_in[0];
    const float* table = (const float*)d_in[1];
    const float* W     = (const float*)d_in[2];
    float*       out   = (float*)d_out;
    int*         hbuf  = (int*)d_ws;   // 32768 ints = 128 KB scratch

    hash_kernel<<<NTOK / 256, 256, 0, stream>>>(ids, hbuf);

    dim3 grid(NTOK / TT, MDIM / 256);   // 512 x 4 blocks, 256 thr = 4 waves
    bigram_kernel<<<grid, 256, 0, stream>>>(hbuf, table, W, out);
}